// Round 11
// baseline (188.546 us; speedup 1.0000x reference)
//
#include <hip/hip_runtime.h>
#include <math.h>

// OHNM loss: pos BCE sum + top-k(600000) negative softplus sum, mean over 800000.
//
// R11: 4 dispatches; the partial-histogram array is scanned ONCE (R10 lesson:
// 64 blocks redundantly scanning 1 MB of partials = 64 MB cross-XCD traffic
// = 64 us).
//  k_main (2048x256): zero-atomic stream pass: pos partial sums + per-WAVE
//    private cand regions via ballot cursor, plain stores (R7/R10-proven).
//  k_hist (64x1024): per-block LDS hist of cand: 4096 fine bins
//    (min((k-K0)>>14, 4095)) counts + softplus-sums; pure-store partials +
//    64-bin coarse collapse (for the two-level scan).
//  k_red (1x1024): derive_hard; pos_sum; coarse scan (16 KB) -> c1 + coarse
//    fsum-suffix; fine scan within c1 (16 KB) -> (b1,r1) + fine fsum-suffix;
//    publishes {hard, b1, r1, ps, sure}. Total reads ~80 KB.
//  k_sel (64x1024): NO scans: stream cand slice, stage boundary-bin keys in
//    LDS -> side buffer (ONE global atomic/block); ticket; winner copies side
//    keys to LDS (coherent atomic reads, R10-proven) and runs exact 3-level
//    (11/11/10-bit) full-key radix select -> out = (ps+sure+sel)/(4p).
// hard mode (cand shortfall / region overflow / boundary bin > LDS / side
// overflow): k_sel winner streams x,y through the same select with R=Kneg,
// total = ps + sel. Exact for ANY input; never taken here.

#define K0 0xBF800000u             // f2key(1.0f)
#define NWAVES 8192                // k_main: 2048 blocks x 4 waves
#define REG 256                    // cand words per wave (lambda=159)
#define NP 64                      // k_hist blocks / partials
#define NSEL 64                    // k_sel blocks
#define NBF 4096                   // fine bins
#define NCB 64                     // coarse bins
#define LBUF 4096                  // boundary staging (words)
#define SIDE_CAP 65536

// ---- ws layout (word offsets) ----
#define OFF_SIDE_CNT 0
#define OFF_FLAGS    1
#define OFF_TICKET   2
#define OFF_PUB_HARD 8
#define OFF_PUB_B1   9
#define OFF_PUB_R1   10
#define OFF_PUB_PS   11            // float
#define OFF_PUB_SURE 12            // float
#define OFF_CNT      128                     // 8192 per-wave counts (|ovf<<31)
#define OFF_POSP     (OFF_CNT + NWAVES)      // 8192 floats
#define OFF_HC       (OFF_POSP + NWAVES)     // 64 x 4096 counts
#define OFF_HF       (OFF_HC + NP * NBF)     // 64 x 4096 floats
#define OFF_CC       (OFF_HF + NP * NBF)     // 64 x 64 coarse counts
#define OFF_CF       (OFF_CC + NP * NCB)     // 64 x 64 coarse floats
#define OFF_SIDE     (OFF_CF + NP * NCB)
#define OFF_CAND     (OFF_SIDE + SIDE_CAP)
#define CANDW        (NWAVES * REG)          // 2,097,152 words (8 MB)

__device__ __forceinline__ unsigned f2key(float x) {
    unsigned u = __float_as_uint(x);
    return (u & 0x80000000u) ? ~u : (u | 0x80000000u);
}
__device__ __forceinline__ float key2f(unsigned k) {
    unsigned u = (k & 0x80000000u) ? (k & 0x7FFFFFFFu) : ~k;
    return __uint_as_float(u);
}
__device__ __forceinline__ float softplusf(float x) {
    return fmaxf(x, 0.0f) + __logf(1.0f + __expf(-fabsf(x)));
}
__device__ __forceinline__ unsigned fbin_of(unsigned k) {
    unsigned b = (k - K0) >> 14;
    return b > (NBF - 1) ? (NBF - 1) : b;
}
__device__ __forceinline__ float wred(float v) {
    v += __shfl_down(v, 32); v += __shfl_down(v, 16); v += __shfl_down(v, 8);
    v += __shfl_down(v, 4);  v += __shfl_down(v, 2);  v += __shfl_down(v, 1);
    return v;
}
// block float-sum; result valid on thread 0
__device__ float bred(float v) {
    __shared__ float sb[16];
    const int lane = threadIdx.x & 63, w = threadIdx.x >> 6;
    const int nw = blockDim.x >> 6;
    v = wred(v);
    if (lane == 0) sb[w] = v;
    __syncthreads();
    float r = 0.0f;
    if (threadIdx.x == 0) for (int i = 0; i < nw; ++i) r += sb[i];
    __syncthreads();
    return r;
}

// hard flag: cand shortfall OR any wave-region overflow. 1024 threads.
__device__ bool derive_hard(const unsigned* __restrict__ ws, unsigned Kneg) {
    __shared__ unsigned rt[16], ro[16];
    __shared__ unsigned flag;
    const int t = threadIdx.x, lane = t & 63, w = t >> 6;
    unsigned tot = 0u, ov = 0u;
    for (unsigned i = t; i < NWAVES; i += 1024) {
        unsigned cc = ws[OFF_CNT + i];
        tot += cc & 0x7FFFFFFFu;
        ov |= cc >> 31;
    }
    for (int o = 32; o; o >>= 1) {
        tot += (unsigned)__shfl_down((int)tot, o);
        ov |= (unsigned)__shfl_down((int)ov, o);
    }
    if (lane == 0) { rt[w] = tot; ro[w] = ov; }
    __syncthreads();
    if (t == 0) {
        unsigned T = 0, O = 0;
        for (int i = 0; i < 16; ++i) { T += rt[i]; O |= ro[i]; }
        flag = (T < Kneg) || O;
    }
    __syncthreads();
    return flag != 0u;
}

// load per-wave counts (min(count,REG)) into LDS table. 1024 threads.
__device__ void load_cnt16(const unsigned* __restrict__ ws, unsigned short* cnt16) {
    for (unsigned i = threadIdx.x; i < NWAVES; i += 1024) {
        unsigned c = ws[OFF_CNT + i] & 0x7FFFFFFFu;
        cnt16[i] = (unsigned short)(c < REG ? c : REG);
    }
    __syncthreads();
}

// descending rank-select over an LDS hist + fsum-above. 1024 threads.
__device__ void scanL(const unsigned* __restrict__ cnt, const float* __restrict__ fsm,
                      int nbins, unsigned R,
                      unsigned* b_out, unsigned* r_out, float* fa_out) {
    __shared__ unsigned sums[1024];
    __shared__ unsigned res[2];
    __shared__ float sred;
    const int t = threadIdx.x;
    const int per = nbins >> 10;           // 1 or 2
    unsigned local[2];
    unsigned s = 0;
    for (int j = 0; j < per; ++j) {
        local[j] = cnt[nbins - 1 - (t * per + j)];
        s += local[j];
    }
    if (t == 0) { res[0] = 0u; res[1] = 1u; sred = 0.0f; }
    sums[t] = s;
    __syncthreads();
    for (int off = 1; off < 1024; off <<= 1) {
        unsigned v = (t >= off) ? sums[t - off] : 0u;
        __syncthreads();
        sums[t] += v;
        __syncthreads();
    }
    const unsigned incl = sums[t], excl = incl - s;
    if (excl < R && incl >= R) {
        unsigned cum = excl;
        for (int j = 0; j < per; ++j) {
            if (cum + local[j] >= R) {
                res[0] = (unsigned)(nbins - 1 - (t * per + j));
                res[1] = R - cum;
                break;
            }
            cum += local[j];
        }
    }
    __syncthreads();
    const unsigned b = res[0];
    float f = 0.0f;
    for (int j = (int)b + 1 + t; j < nbins; j += 1024) f += fsm[j];
    f = wred(f);
    if ((t & 63) == 0) atomicAdd(&sred, f);
    __syncthreads();
    *b_out = b;
    *r_out = res[1];
    if (t == 0) *fa_out = sred;
    __syncthreads();
}

// exact top-R softplus sum by 3-level (11/11/10-bit) radix select on FULL
// 32-bit keys. One block, 1024 threads. Source: LDS key buffer (stream=false)
// or negatives streamed from x,y (stream=true). Result valid on thread 0.
__device__ float select_any(const unsigned* __restrict__ lkeys, unsigned m3,
                            const float* __restrict__ x, const float* __restrict__ y,
                            int n, bool stream, unsigned R) {
    __shared__ unsigned cnt[2048];
    __shared__ float fsm[2048];
    const int t = threadIdx.x;
    unsigned prefix = 0u, mask = 0u;
    float above = 0.0f;                    // thread 0 only
    const int sh[3] = {21, 10, 0};
    const int nb[3] = {2048, 2048, 1024};
    for (int l = 0; l < 3; ++l) {
        for (int i = t; i < nb[l]; i += 1024) { cnt[i] = 0u; fsm[i] = 0.0f; }
        __syncthreads();
        if (!stream) {
            for (unsigned i = t; i < m3; i += 1024) {
                unsigned k = lkeys[i];
                if ((k & mask) == prefix) {
                    unsigned b = (k >> sh[l]) & (unsigned)(nb[l] - 1);
                    atomicAdd(&cnt[b], 1u);
                    atomicAdd(&fsm[b], softplusf(key2f(k)));
                }
            }
        } else {
            for (unsigned i = t; i < (unsigned)n; i += 1024) {
                if (y[i] == 0.0f) {
                    unsigned k = f2key(x[i]);
                    if ((k & mask) == prefix) {
                        unsigned b = (k >> sh[l]) & (unsigned)(nb[l] - 1);
                        atomicAdd(&cnt[b], 1u);
                        atomicAdd(&fsm[b], softplusf(key2f(k)));
                    }
                }
            }
        }
        __syncthreads();
        unsigned b, r;
        float fa;
        scanL(cnt, fsm, nb[l], R, &b, &r, &fa);
        if (t == 0) above += fa;
        R = r;
        prefix |= b << sh[l];
        mask |= (unsigned)(nb[l] - 1) << sh[l];
        __syncthreads();
    }
    return above + (float)R * softplusf(key2f(prefix));
}

// ---- k_main: pos partial sums + per-wave-region compact. ZERO atomics. ----
__global__ __launch_bounds__(256)
void k_main(const float* __restrict__ x, const float* __restrict__ y,
            unsigned* __restrict__ ws, unsigned cap_words, int n) {
    const int tid = threadIdx.x;
    const int lane = tid & 63;
    const unsigned waveid = blockIdx.x * 4 + (tid >> 6);
    unsigned* cand = ws + OFF_CAND;
    const unsigned base = waveid * REG;

    if (blockIdx.x == 0)                   // zero control/pub words
        for (int i = tid; i < 128; i += 256) ws[i] = 0u;

    float ps = 0.0f;
    unsigned cur = 0u, ovf = 0u;
    const int n4 = n >> 2;
    const float4* x4 = (const float4*)x;
    const float4* y4 = (const float4*)y;
    const unsigned gtid = blockIdx.x * blockDim.x + tid;
    const unsigned gstride = gridDim.x * blockDim.x;
    for (unsigned i = gtid; i < (unsigned)n4; i += gstride) {
        float4 xv = x4[i];
        float4 yv = y4[i];
        float xs[4] = {xv.x, xv.y, xv.z, xv.w};
        float ys[4] = {yv.x, yv.y, yv.z, yv.w};
#pragma unroll
        for (int c = 0; c < 4; ++c) {
            bool pos = ys[c] > 0.0f;
            if (pos) ps += softplusf(-xs[c]);
            unsigned k = f2key(xs[c]);
            bool cnd = (!pos) && (k >= K0);
            unsigned long long mask = __ballot(cnd);
            if (mask) {
                if (cnd) {
                    unsigned slot = cur + (unsigned)__popcll(mask & ((1ull << lane) - 1ull));
                    unsigned gi = base + slot;
                    if (slot < REG && gi < cap_words) cand[gi] = k;
                    else ovf = 1u;
                }
                cur += (unsigned)__popcll(mask);
            }
        }
    }
    // tail (n % 4): wave 0 only; ballot keeps cur wave-uniform
    if (waveid == 0) {
        for (int i = (n & ~3) + lane; i < n; i += 64) {
            float xs = x[i];
            bool pos = y[i] > 0.0f;
            if (pos) ps += softplusf(-xs);
            unsigned k = f2key(xs);
            bool cnd = (!pos) && (k >= K0);
            unsigned long long mask = __ballot(cnd);
            if (mask) {
                if (cnd) {
                    unsigned slot = cur + (unsigned)__popcll(mask & ((1ull << lane) - 1ull));
                    unsigned gi = base + slot;
                    if (slot < REG && gi < cap_words) cand[gi] = k;
                    else ovf = 1u;
                }
                cur += (unsigned)__popcll(mask);
            }
        }
    }
    if (base + REG > cap_words) ovf = 1u;
    ps = wred(ps);
    unsigned anyovf = (__ballot(ovf != 0u) != 0ull) ? 0x80000000u : 0u;
    if (lane == 0) {
        ws[OFF_CNT + waveid] = (cur & 0x7FFFFFFFu) | anyovf;
        ((float*)ws)[OFF_POSP + waveid] = ps;
    }
}

// ---- k_hist (64x1024): fine+coarse partial hists over cand. Pure stores. ----
__global__ __launch_bounds__(1024)
void k_hist(unsigned* __restrict__ ws) {
    __shared__ unsigned hc[NBF];
    __shared__ float hf[NBF];
    __shared__ unsigned short cnt16[NWAVES];
    __shared__ unsigned rcu[1024];
    __shared__ float rcf[1024];
    const int t = threadIdx.x;
    load_cnt16(ws, cnt16);
    for (int i = t; i < NBF; i += 1024) { hc[i] = 0u; hf[i] = 0.0f; }
    __syncthreads();
    const unsigned* cand = ws + OFF_CAND;
    for (unsigned i = blockIdx.x * 1024 + t; i < (unsigned)CANDW; i += NP * 1024) {
        if ((i & (REG - 1)) < (unsigned)cnt16[i >> 8]) {
            unsigned k = cand[i];
            unsigned b = fbin_of(k);
            atomicAdd(&hc[b], 1u);
            atomicAdd(&hf[b], softplusf(key2f(k)));
        }
    }
    __syncthreads();
    for (int i = t; i < NBF; i += 1024) {                       // pure stores
        ws[OFF_HC + blockIdx.x * NBF + i] = hc[i];
        ((float*)ws)[OFF_HF + blockIdx.x * NBF + i] = hf[i];
    }
    // coarse collapse: thread t handles (cb = t>>4, q = t&15): 4 fine bins
    {
        const int cb = t >> 4, q = t & 15;
        unsigned cs = 0; float cf = 0.0f;
#pragma unroll
        for (int j = 0; j < 4; ++j) {
            cs += hc[cb * 64 + q * 4 + j];
            cf += hf[cb * 64 + q * 4 + j];
        }
        rcu[t] = cs; rcf[t] = cf;
    }
    __syncthreads();
    if (t < NCB) {
        unsigned s = 0; float f = 0.0f;
        for (int q = 0; q < 16; ++q) { s += rcu[t * 16 + q]; f += rcf[t * 16 + q]; }
        ws[OFF_CC + blockIdx.x * NCB + t] = s;
        ((float*)ws)[OFF_CF + blockIdx.x * NCB + t] = f;
    }
}

// ---- k_red (1x1024): hard + pos + two-level scan -> publish ----
__global__ __launch_bounds__(1024)
void k_red(unsigned* __restrict__ ws, const int* __restrict__ pos_num,
           unsigned side_cap) {
    __shared__ unsigned rcu[1024];
    __shared__ float rcf[1024];
    __shared__ unsigned csum[NCB];
    __shared__ float cfs[NCB];
    __shared__ unsigned sres[4];   // c1, rc, b1, r1
    __shared__ float sfs[2];       // sure_c, sure_f
    const int t = threadIdx.x;
    const unsigned Kneg = (unsigned)(pos_num[0] * 3);
    const bool hard = derive_hard(ws, Kneg);
    float ps = 0.0f;
    for (unsigned i = t; i < NWAVES; i += 1024) ps += ((float*)ws)[OFF_POSP + i];
    ps = bred(ps);                 // thread 0
    unsigned pub_hard = hard ? 1u : 0u;
    unsigned b1 = 0, r1 = 1;
    float sure = 0.0f;
    if (!hard) {
        // coarse sums: thread (cb=t>>4, q=t&15) over p = q*4..q*4+3
        {
            const int cb = t >> 4, q = t & 15;
            unsigned s = 0; float f = 0.0f;
#pragma unroll
            for (int j = 0; j < 4; ++j) {
                s += ws[OFF_CC + (q * 4 + j) * NCB + cb];
                f += ((float*)ws)[OFF_CF + (q * 4 + j) * NCB + cb];
            }
            rcu[t] = s; rcf[t] = f;
        }
        __syncthreads();
        if (t < NCB) {
            unsigned s = 0; float f = 0.0f;
            for (int q = 0; q < 16; ++q) { s += rcu[t * 16 + q]; f += rcf[t * 16 + q]; }
            csum[t] = s; cfs[t] = f;
        }
        __syncthreads();
        if (t == 0) {              // serial coarse descent (64 iters)
            unsigned R = Kneg, c1 = 0, rc = 1;
            float sc = 0.0f;
            for (int cb = NCB - 1; cb >= 0; --cb) {
                if (csum[cb] >= R) { c1 = (unsigned)cb; rc = R; break; }
                R -= csum[cb];
                sc += cfs[cb];
            }
            sres[0] = c1; sres[1] = rc; sfs[0] = sc;
        }
        __syncthreads();
        const unsigned c1 = sres[0];
        // fine sums within c1: thread (fb=t>>4, q=t&15) over p = q*4..q*4+3
        {
            const int fb = t >> 4, q = t & 15;
            unsigned s = 0; float f = 0.0f;
#pragma unroll
            for (int j = 0; j < 4; ++j) {
                s += ws[OFF_HC + (q * 4 + j) * NBF + c1 * 64 + fb];
                f += ((float*)ws)[OFF_HF + (q * 4 + j) * NBF + c1 * 64 + fb];
            }
            rcu[t] = s; rcf[t] = f;
        }
        __syncthreads();
        if (t < 64) {
            unsigned s = 0; float f = 0.0f;
            for (int q = 0; q < 16; ++q) { s += rcu[t * 16 + q]; f += rcf[t * 16 + q]; }
            csum[t] = s; cfs[t] = f;
        }
        __syncthreads();
        if (t == 0) {              // serial fine descent
            unsigned R = sres[1], fb1 = 0, rr = 1;
            float sf = 0.0f;
            for (int fb = 63; fb >= 0; --fb) {
                if (csum[fb] >= R) { fb1 = (unsigned)fb; rr = R; break; }
                R -= csum[fb];
                sf += cfs[fb];
            }
            sres[2] = sres[0] * 64 + fb1;   // global fine bin
            sres[3] = rr;
            sfs[1] = sf;
            // boundary-bin population must fit LDS staging + side buffer
            unsigned bc = csum[fb1];
            if (bc > LBUF || bc > side_cap) pub_hard = 1u;
        }
        __syncthreads();
        b1 = sres[2]; r1 = sres[3];
        sure = sfs[0] + sfs[1];
        if (t == 0 && pub_hard) { /* fall back below */ }
    }
    if (t == 0) {
        ws[OFF_PUB_HARD] = pub_hard;
        ws[OFF_PUB_B1] = b1;
        ws[OFF_PUB_R1] = r1;
        ((float*)ws)[OFF_PUB_PS] = ps;
        ((float*)ws)[OFF_PUB_SURE] = pub_hard ? 0.0f : sure;
    }
}

// ---- k_sel (64x1024): boundary extract; ticket; winner selects -> out ----
__global__ __launch_bounds__(1024)
void k_sel(const float* __restrict__ x, const float* __restrict__ y,
           unsigned* __restrict__ ws, const int* __restrict__ pos_num,
           float* __restrict__ out, int n, unsigned side_cap) {
    __shared__ unsigned lbuf[LBUF];
    __shared__ unsigned short cnt16[NWAVES];
    __shared__ unsigned lcnt, gbase, sticket;
    const int t = threadIdx.x;
    const int p = pos_num[0];
    const unsigned Kneg = (unsigned)(p * 3);
    const unsigned hard = ws[OFF_PUB_HARD];        // prev dispatch: plain ok
    const unsigned b1 = ws[OFF_PUB_B1];
    const unsigned r1 = ws[OFF_PUB_R1];
    const float ps = ((float*)ws)[OFF_PUB_PS];
    const float sure = ((float*)ws)[OFF_PUB_SURE];
    if (!hard) {
        load_cnt16(ws, cnt16);
        if (t == 0) lcnt = 0u;
        __syncthreads();
        const unsigned* cand = ws + OFF_CAND;
        unsigned* side = ws + OFF_SIDE;
        for (unsigned i = blockIdx.x * 1024 + t; i < (unsigned)CANDW; i += NSEL * 1024) {
            if ((i & (REG - 1)) < (unsigned)cnt16[i >> 8]) {
                unsigned k = cand[i];
                if (fbin_of(k) == b1) {            // ~35 hits/block
                    unsigned q = atomicAdd(&lcnt, 1u);
                    if (q < LBUF) lbuf[q] = k;
                }
            }
        }
        __syncthreads();
        const unsigned m = lcnt < LBUF ? lcnt : LBUF;
        if (t == 0) {
            gbase = atomicAdd(&ws[OFF_SIDE_CNT], m);        // ONE per block
            if (lcnt > LBUF) atomicOr(&ws[OFF_FLAGS], 1u);
        }
        __syncthreads();
        unsigned oob = 0u;
        for (unsigned i = t; i < m; i += 1024) {
            unsigned gi = gbase + i;
            if (gi < side_cap) side[gi] = lbuf[i];
            else oob = 1u;
        }
        if (oob) atomicOr(&ws[OFF_FLAGS], 1u);
    }
    // ---- ticket: last block finalizes ----
    __threadfence();
    if (t == 0) sticket = atomicAdd(&ws[OFF_TICKET], 1u);
    __syncthreads();
    if (sticket != NSEL - 1) return;
    bool whard = hard != 0u;
    unsigned m3 = 0;
    if (!whard) {
        if (atomicOr(&ws[OFF_FLAGS], 0u)) whard = true;
        else {
            m3 = atomicAdd(&ws[OFF_SIDE_CNT], 0u);
            if (m3 > LBUF || m3 > side_cap) whard = true;
        }
    }
    float total;
    if (!whard) {
        for (unsigned i = t; i < m3; i += 1024)
            lbuf[i] = atomicOr(&ws[OFF_SIDE + i], 0u);      // coherent copy
        __syncthreads();
        total = ps + sure + select_any(lbuf, m3, x, y, n, false, r1);
    } else {
        total = ps + select_any(nullptr, 0u, x, y, n, true, Kneg);
    }
    if (t == 0) out[0] = total / (float)(4 * p);
}

extern "C" void kernel_launch(void* const* d_in, const int* in_sizes, int n_in,
                              void* d_out, int out_size, void* d_ws, size_t ws_size,
                              hipStream_t stream) {
    const float* x = (const float*)d_in[0];
    const float* y = (const float*)d_in[1];
    const int* pos_num = (const int*)d_in[2];
    float* out = (float*)d_out;
    const int n = in_sizes[0];

    unsigned* ws = (unsigned*)d_ws;
    const size_t wsw = ws_size / 4;
    unsigned cap_words = 0u;
    if (wsw > (size_t)OFF_CAND) cap_words = (unsigned)(wsw - OFF_CAND);
    if (cap_words > (unsigned)CANDW) cap_words = (unsigned)CANDW;
    unsigned side_cap = SIDE_CAP;              // layout guarantees fit if cap>0
    if (wsw <= (size_t)OFF_CAND) side_cap = 0u;

    k_main<<<2048, 256, 0, stream>>>(x, y, ws, cap_words, n);
    k_hist<<<NP, 1024, 0, stream>>>(ws);
    k_red<<<1, 1024, 0, stream>>>(ws, pos_num, side_cap);
    k_sel<<<NSEL, 1024, 0, stream>>>(x, y, ws, pos_num, out, n, side_cap);
}

// Round 12
// 182.267 us; speedup vs baseline: 1.0344x; 1.0344x over previous
//
#include <hip/hip_runtime.h>
#include <math.h>

// OHNM loss: pos BCE sum + top-k(600000) negative softplus sum, mean over 800000.
//
// R12: 4 dispatches, NO __threadfence / ticket anywhere (R11 lesson: k_sel's
// device-scope fence + in-kernel winner finalize cost ~35us even with all data
// L2-resident; kernel boundaries are free device-wide barriers).
//  k_main (2048x256): zero-atomic stream pass: pos partial sums + per-WAVE
//    private cand regions via ballot cursor, plain stores (R7-proven).
//  k_hist (64x1024): per-block LDS fine hist of cand (4096 bins:
//    min((k-K0)>>14,4095)) counts + softplus sums; pure-store partials +
//    64-bin coarse collapse (R11-proven).
//  k_sel (64x1024): per-block two-level scan (coarse 64 -> fine 64 within c1,
//    ~32KB reads/block) -> b1; stream cand; stage boundary-bin keys in LDS ->
//    side buffer (ONE global atomic/block). No fence. No finalize.
//  k_fin (1x1024): re-derive (b1,r1,sure) with fsums (~64KB) + pos_sum (32KB);
//    plain-load side keys; exact 3-level (11/11/10-bit) full-key radix select
//    -> out = (ps + sure + sel)/(4p).
// hard mode (cand shortfall / region overflow / staging or side overflow /
// m3 > LBUF_FIN): k_fin streams x,y through the same select with R=Kneg,
// total = ps + sel. Exact for ANY input; never taken here.

#define K0 0xBF800000u             // f2key(1.0f)
#define NWAVES 8192                // k_main: 2048 blocks x 4 waves
#define REG 256                    // cand words per wave (lambda=159)
#define NP 64                      // k_hist blocks / partials
#define NSEL 64                    // k_sel blocks
#define NBF 4096                   // fine bins
#define NCB 64                     // coarse bins
#define LBUF 4096                  // k_sel per-block staging (words)
#define LBUF_FIN 8192              // k_fin select buffer (words)
#define SIDE_CAP 65536

// ---- ws layout (word offsets) ----
#define OFF_SIDE_CNT 0
#define OFF_FLAGS    1
#define OFF_CNT      128                     // 8192 per-wave counts (|ovf<<31)
#define OFF_POSP     (OFF_CNT + NWAVES)      // 8192 floats
#define OFF_HC       (OFF_POSP + NWAVES)     // 64 x 4096 counts
#define OFF_HF       (OFF_HC + NP * NBF)     // 64 x 4096 floats
#define OFF_CC       (OFF_HF + NP * NBF)     // 64 x 64 coarse counts
#define OFF_CF       (OFF_CC + NP * NCB)     // 64 x 64 coarse floats
#define OFF_SIDE     (OFF_CF + NP * NCB)
#define OFF_CAND     (OFF_SIDE + SIDE_CAP)
#define CANDW        (NWAVES * REG)          // 2,097,152 words (8 MB)

__device__ __forceinline__ unsigned f2key(float x) {
    unsigned u = __float_as_uint(x);
    return (u & 0x80000000u) ? ~u : (u | 0x80000000u);
}
__device__ __forceinline__ float key2f(unsigned k) {
    unsigned u = (k & 0x80000000u) ? (k & 0x7FFFFFFFu) : ~k;
    return __uint_as_float(u);
}
__device__ __forceinline__ float softplusf(float x) {
    return fmaxf(x, 0.0f) + __logf(1.0f + __expf(-fabsf(x)));
}
__device__ __forceinline__ unsigned fbin_of(unsigned k) {
    unsigned b = (k - K0) >> 14;
    return b > (NBF - 1) ? (NBF - 1) : b;
}
__device__ __forceinline__ float wred(float v) {
    v += __shfl_down(v, 32); v += __shfl_down(v, 16); v += __shfl_down(v, 8);
    v += __shfl_down(v, 4);  v += __shfl_down(v, 2);  v += __shfl_down(v, 1);
    return v;
}
// block float-sum; result valid on thread 0
__device__ float bred(float v) {
    __shared__ float sb[16];
    const int lane = threadIdx.x & 63, w = threadIdx.x >> 6;
    const int nw = blockDim.x >> 6;
    v = wred(v);
    if (lane == 0) sb[w] = v;
    __syncthreads();
    float r = 0.0f;
    if (threadIdx.x == 0) for (int i = 0; i < nw; ++i) r += sb[i];
    __syncthreads();
    return r;
}

// hard flag (cand shortfall OR wave-region overflow) + optional cnt16 fill.
// 1024 threads, one pass over the 8192-word count array.
__device__ bool hard_and_cnt16(const unsigned* __restrict__ ws, unsigned Kneg,
                               unsigned short* cnt16) {
    __shared__ unsigned rt[16], ro[16];
    __shared__ unsigned flag;
    const int t = threadIdx.x, lane = t & 63, w = t >> 6;
    unsigned tot = 0u, ov = 0u;
    for (unsigned i = t; i < NWAVES; i += 1024) {
        unsigned cc = ws[OFF_CNT + i];
        unsigned c = cc & 0x7FFFFFFFu;
        tot += c;
        ov |= cc >> 31;
        if (cnt16) cnt16[i] = (unsigned short)(c < REG ? c : REG);
    }
    for (int o = 32; o; o >>= 1) {
        tot += (unsigned)__shfl_down((int)tot, o);
        ov |= (unsigned)__shfl_down((int)ov, o);
    }
    if (lane == 0) { rt[w] = tot; ro[w] = ov; }
    __syncthreads();
    if (t == 0) {
        unsigned T = 0, O = 0;
        for (int i = 0; i < 16; ++i) { T += rt[i]; O |= ro[i]; }
        flag = (T < Kneg) || O;
    }
    __syncthreads();
    return flag != 0u;
}

// two-level rank descent (coarse 64 -> fine 64 within c1) over the partial
// hists. ~32KB reads (64KB with fsums). 1024 threads; outputs uniform.
__device__ void derive_b1(const unsigned* __restrict__ ws, unsigned Kneg,
                          bool want_f, unsigned* b1_out, unsigned* r1_out,
                          float* sure_out) {
    __shared__ unsigned rcu[1024];
    __shared__ float rcf[1024];
    __shared__ unsigned csum[NCB];
    __shared__ float cfs[NCB];
    __shared__ unsigned sres[4];
    __shared__ float sfs[2];
    const int t = threadIdx.x;
    {   // coarse: thread (cb=t>>4, q=t&15) sums partials q*4..q*4+3
        const int cb = t >> 4, q = t & 15;
        unsigned s = 0; float f = 0.0f;
#pragma unroll
        for (int j = 0; j < 4; ++j) {
            s += ws[OFF_CC + (q * 4 + j) * NCB + cb];
            if (want_f) f += ((const float*)ws)[OFF_CF + (q * 4 + j) * NCB + cb];
        }
        rcu[t] = s; rcf[t] = f;
    }
    __syncthreads();
    if (t < NCB) {
        unsigned s = 0; float f = 0.0f;
        for (int q = 0; q < 16; ++q) { s += rcu[t * 16 + q]; f += rcf[t * 16 + q]; }
        csum[t] = s; cfs[t] = f;
    }
    __syncthreads();
    if (t == 0) {                  // serial coarse descent
        unsigned R = Kneg, c1 = 0, rc = 1;
        float sc = 0.0f;
        for (int cb = NCB - 1; cb >= 0; --cb) {
            if (csum[cb] >= R) { c1 = (unsigned)cb; rc = R; break; }
            R -= csum[cb];
            sc += cfs[cb];
        }
        sres[0] = c1; sres[1] = rc; sfs[0] = sc;
    }
    __syncthreads();
    const unsigned c1 = sres[0];
    {   // fine within c1
        const int fb = t >> 4, q = t & 15;
        unsigned s = 0; float f = 0.0f;
#pragma unroll
        for (int j = 0; j < 4; ++j) {
            s += ws[OFF_HC + (q * 4 + j) * NBF + c1 * 64 + fb];
            if (want_f) f += ((const float*)ws)[OFF_HF + (q * 4 + j) * NBF + c1 * 64 + fb];
        }
        rcu[t] = s; rcf[t] = f;
    }
    __syncthreads();
    if (t < 64) {
        unsigned s = 0; float f = 0.0f;
        for (int q = 0; q < 16; ++q) { s += rcu[t * 16 + q]; f += rcf[t * 16 + q]; }
        csum[t] = s; cfs[t] = f;
    }
    __syncthreads();
    if (t == 0) {                  // serial fine descent
        unsigned R = sres[1], fb1 = 0, rr = 1;
        float sf = 0.0f;
        for (int fb = 63; fb >= 0; --fb) {
            if (csum[fb] >= R) { fb1 = (unsigned)fb; rr = R; break; }
            R -= csum[fb];
            sf += cfs[fb];
        }
        sres[2] = sres[0] * 64 + fb1;
        sres[3] = rr;
        sfs[1] = sfs[0] + sf;
    }
    __syncthreads();
    *b1_out = sres[2];
    *r1_out = sres[3];
    if (sure_out) *sure_out = sfs[1];
    __syncthreads();
}

// descending rank-select over an LDS hist + fsum-above. 1024 threads.
__device__ void scanL(const unsigned* __restrict__ cnt, const float* __restrict__ fsm,
                      int nbins, unsigned R,
                      unsigned* b_out, unsigned* r_out, float* fa_out) {
    __shared__ unsigned sums[1024];
    __shared__ unsigned res[2];
    __shared__ float sred;
    const int t = threadIdx.x;
    const int per = nbins >> 10;           // 1 or 2
    unsigned local[2];
    unsigned s = 0;
    for (int j = 0; j < per; ++j) {
        local[j] = cnt[nbins - 1 - (t * per + j)];
        s += local[j];
    }
    if (t == 0) { res[0] = 0u; res[1] = 1u; sred = 0.0f; }
    sums[t] = s;
    __syncthreads();
    for (int off = 1; off < 1024; off <<= 1) {
        unsigned v = (t >= off) ? sums[t - off] : 0u;
        __syncthreads();
        sums[t] += v;
        __syncthreads();
    }
    const unsigned incl = sums[t], excl = incl - s;
    if (excl < R && incl >= R) {
        unsigned cum = excl;
        for (int j = 0; j < per; ++j) {
            if (cum + local[j] >= R) {
                res[0] = (unsigned)(nbins - 1 - (t * per + j));
                res[1] = R - cum;
                break;
            }
            cum += local[j];
        }
    }
    __syncthreads();
    const unsigned b = res[0];
    float f = 0.0f;
    for (int j = (int)b + 1 + t; j < nbins; j += 1024) f += fsm[j];
    f = wred(f);
    if ((t & 63) == 0) atomicAdd(&sred, f);
    __syncthreads();
    *b_out = b;
    *r_out = res[1];
    if (t == 0) *fa_out = sred;
    __syncthreads();
}

// exact top-R softplus sum by 3-level (11/11/10-bit) radix select on FULL
// 32-bit keys. One block, 1024 threads. Source: LDS key buffer (stream=false)
// or negatives streamed from x,y (stream=true). Result valid on thread 0.
__device__ float select_any(const unsigned* __restrict__ lkeys, unsigned m3,
                            const float* __restrict__ x, const float* __restrict__ y,
                            int n, bool stream, unsigned R) {
    __shared__ unsigned cnt[2048];
    __shared__ float fsm[2048];
    const int t = threadIdx.x;
    unsigned prefix = 0u, mask = 0u;
    float above = 0.0f;                    // thread 0 only
    const int sh[3] = {21, 10, 0};
    const int nb[3] = {2048, 2048, 1024};
    for (int l = 0; l < 3; ++l) {
        for (int i = t; i < nb[l]; i += 1024) { cnt[i] = 0u; fsm[i] = 0.0f; }
        __syncthreads();
        if (!stream) {
            for (unsigned i = t; i < m3; i += 1024) {
                unsigned k = lkeys[i];
                if ((k & mask) == prefix) {
                    unsigned b = (k >> sh[l]) & (unsigned)(nb[l] - 1);
                    atomicAdd(&cnt[b], 1u);
                    atomicAdd(&fsm[b], softplusf(key2f(k)));
                }
            }
        } else {
            for (unsigned i = t; i < (unsigned)n; i += 1024) {
                if (y[i] == 0.0f) {
                    unsigned k = f2key(x[i]);
                    if ((k & mask) == prefix) {
                        unsigned b = (k >> sh[l]) & (unsigned)(nb[l] - 1);
                        atomicAdd(&cnt[b], 1u);
                        atomicAdd(&fsm[b], softplusf(key2f(k)));
                    }
                }
            }
        }
        __syncthreads();
        unsigned b, r;
        float fa;
        scanL(cnt, fsm, nb[l], R, &b, &r, &fa);
        if (t == 0) above += fa;
        R = r;
        prefix |= b << sh[l];
        mask |= (unsigned)(nb[l] - 1) << sh[l];
        __syncthreads();
    }
    return above + (float)R * softplusf(key2f(prefix));
}

// ---- k_main: pos partial sums + per-wave-region compact. ZERO atomics. ----
__global__ __launch_bounds__(256)
void k_main(const float* __restrict__ x, const float* __restrict__ y,
            unsigned* __restrict__ ws, unsigned cap_words, int n) {
    const int tid = threadIdx.x;
    const int lane = tid & 63;
    const unsigned waveid = blockIdx.x * 4 + (tid >> 6);
    unsigned* cand = ws + OFF_CAND;
    const unsigned base = waveid * REG;

    if (blockIdx.x == 0)                   // zero control words
        for (int i = tid; i < 128; i += 256) ws[i] = 0u;

    float ps = 0.0f;
    unsigned cur = 0u, ovf = 0u;
    const int n4 = n >> 2;
    const float4* x4 = (const float4*)x;
    const float4* y4 = (const float4*)y;
    const unsigned gtid = blockIdx.x * blockDim.x + tid;
    const unsigned gstride = gridDim.x * blockDim.x;
    for (unsigned i = gtid; i < (unsigned)n4; i += gstride) {
        float4 xv = x4[i];
        float4 yv = y4[i];
        float xs[4] = {xv.x, xv.y, xv.z, xv.w};
        float ys[4] = {yv.x, yv.y, yv.z, yv.w};
#pragma unroll
        for (int c = 0; c < 4; ++c) {
            bool pos = ys[c] > 0.0f;
            if (pos) ps += softplusf(-xs[c]);
            unsigned k = f2key(xs[c]);
            bool cnd = (!pos) && (k >= K0);
            unsigned long long mask = __ballot(cnd);
            if (mask) {
                if (cnd) {
                    unsigned slot = cur + (unsigned)__popcll(mask & ((1ull << lane) - 1ull));
                    unsigned gi = base + slot;
                    if (slot < REG && gi < cap_words) cand[gi] = k;
                    else ovf = 1u;
                }
                cur += (unsigned)__popcll(mask);
            }
        }
    }
    // tail (n % 4): wave 0 only; ballot keeps cur wave-uniform
    if (waveid == 0) {
        for (int i = (n & ~3) + lane; i < n; i += 64) {
            float xs = x[i];
            bool pos = y[i] > 0.0f;
            if (pos) ps += softplusf(-xs);
            unsigned k = f2key(xs);
            bool cnd = (!pos) && (k >= K0);
            unsigned long long mask = __ballot(cnd);
            if (mask) {
                if (cnd) {
                    unsigned slot = cur + (unsigned)__popcll(mask & ((1ull << lane) - 1ull));
                    unsigned gi = base + slot;
                    if (slot < REG && gi < cap_words) cand[gi] = k;
                    else ovf = 1u;
                }
                cur += (unsigned)__popcll(mask);
            }
        }
    }
    if (base + REG > cap_words) ovf = 1u;
    ps = wred(ps);
    unsigned anyovf = (__ballot(ovf != 0u) != 0ull) ? 0x80000000u : 0u;
    if (lane == 0) {
        ws[OFF_CNT + waveid] = (cur & 0x7FFFFFFFu) | anyovf;
        ((float*)ws)[OFF_POSP + waveid] = ps;
    }
}

// ---- k_hist (64x1024): fine+coarse partial hists over cand. Pure stores. ----
__global__ __launch_bounds__(1024)
void k_hist(unsigned* __restrict__ ws, const int* __restrict__ pos_num) {
    __shared__ unsigned hc[NBF];
    __shared__ float hf[NBF];
    __shared__ unsigned short cnt16[NWAVES];
    __shared__ unsigned rcu[1024];
    __shared__ float rcf[1024];
    const int t = threadIdx.x;
    const unsigned Kneg = (unsigned)(pos_num[0] * 3);
    if (hard_and_cnt16(ws, Kneg, cnt16)) return;    // k_fin streams in hard mode
    for (int i = t; i < NBF; i += 1024) { hc[i] = 0u; hf[i] = 0.0f; }
    __syncthreads();
    const unsigned* cand = ws + OFF_CAND;
    for (unsigned i = blockIdx.x * 1024 + t; i < (unsigned)CANDW; i += NP * 1024) {
        if ((i & (REG - 1)) < (unsigned)cnt16[i >> 8]) {
            unsigned k = cand[i];
            unsigned b = fbin_of(k);
            atomicAdd(&hc[b], 1u);
            atomicAdd(&hf[b], softplusf(key2f(k)));
        }
    }
    __syncthreads();
    for (int i = t; i < NBF; i += 1024) {                       // pure stores
        ws[OFF_HC + blockIdx.x * NBF + i] = hc[i];
        ((float*)ws)[OFF_HF + blockIdx.x * NBF + i] = hf[i];
    }
    // coarse collapse: thread (cb=t>>4, q=t&15) sums 4 fine bins
    {
        const int cb = t >> 4, q = t & 15;
        unsigned cs = 0; float cf = 0.0f;
#pragma unroll
        for (int j = 0; j < 4; ++j) {
            cs += hc[cb * 64 + q * 4 + j];
            cf += hf[cb * 64 + q * 4 + j];
        }
        rcu[t] = cs; rcf[t] = cf;
    }
    __syncthreads();
    if (t < NCB) {
        unsigned s = 0; float f = 0.0f;
        for (int q = 0; q < 16; ++q) { s += rcu[t * 16 + q]; f += rcf[t * 16 + q]; }
        ws[OFF_CC + blockIdx.x * NCB + t] = s;
        ((float*)ws)[OFF_CF + blockIdx.x * NCB + t] = f;
    }
}

// ---- k_sel (64x1024): derive b1; boundary extract -> side. No fence. ----
__global__ __launch_bounds__(1024)
void k_sel(unsigned* __restrict__ ws, const int* __restrict__ pos_num,
           unsigned side_cap) {
    __shared__ unsigned lbuf[LBUF];
    __shared__ unsigned short cnt16[NWAVES];
    __shared__ unsigned lcnt, gbase;
    const int t = threadIdx.x;
    const unsigned Kneg = (unsigned)(pos_num[0] * 3);
    if (hard_and_cnt16(ws, Kneg, cnt16)) return;
    unsigned b1, r1;
    derive_b1(ws, Kneg, false, &b1, &r1, nullptr);  // counts only, ~32KB reads
    if (t == 0) lcnt = 0u;
    __syncthreads();
    const unsigned* cand = ws + OFF_CAND;
    unsigned* side = ws + OFF_SIDE;
    for (unsigned i = blockIdx.x * 1024 + t; i < (unsigned)CANDW; i += NSEL * 1024) {
        if ((i & (REG - 1)) < (unsigned)cnt16[i >> 8]) {
            unsigned k = cand[i];
            if (fbin_of(k) == b1) {            // ~35 hits/block
                unsigned q = atomicAdd(&lcnt, 1u);
                if (q < LBUF) lbuf[q] = k;
            }
        }
    }
    __syncthreads();
    const unsigned m = lcnt < LBUF ? lcnt : LBUF;
    if (t == 0) {
        gbase = atomicAdd(&ws[OFF_SIDE_CNT], m);   // ONE per block
        if (lcnt > LBUF) atomicOr(&ws[OFF_FLAGS], 1u);
    }
    __syncthreads();
    unsigned oob = 0u;
    for (unsigned i = t; i < m; i += 1024) {
        unsigned gi = gbase + i;
        if (gi < side_cap) side[gi] = lbuf[i];
        else oob = 1u;
    }
    if (oob) atomicOr(&ws[OFF_FLAGS], 1u);
}

// ---- k_fin (1x1024): re-derive; plain-load side; select; out ----
__global__ __launch_bounds__(1024)
void k_fin(const float* __restrict__ x, const float* __restrict__ y,
           unsigned* __restrict__ ws, const int* __restrict__ pos_num,
           float* __restrict__ out, int n, unsigned side_cap) {
    __shared__ unsigned lbuf[LBUF_FIN];
    const int t = threadIdx.x;
    const int p = pos_num[0];
    const unsigned Kneg = (unsigned)(p * 3);
    bool hard = hard_and_cnt16(ws, Kneg, (unsigned short*)nullptr);
    float ps = 0.0f;
    for (unsigned i = t; i < NWAVES; i += 1024) ps += ((float*)ws)[OFF_POSP + i];
    ps = bred(ps);                         // thread 0
    unsigned m3 = 0, r1 = Kneg;
    float sure = 0.0f;
    if (!hard) {
        unsigned b1;
        derive_b1(ws, Kneg, true, &b1, &r1, &sure);
        m3 = ws[OFF_SIDE_CNT];             // prev dispatch: plain read ok
        if (ws[OFF_FLAGS] || m3 > LBUF_FIN || m3 > side_cap) hard = true;
    }
    float total;
    if (!hard) {
        for (unsigned i = t; i < m3; i += 1024)
            lbuf[i] = ws[OFF_SIDE + i];    // plain loads (kernel boundary)
        __syncthreads();
        total = ps + sure + select_any(lbuf, m3, x, y, n, false, r1);
    } else {
        total = ps + select_any(nullptr, 0u, x, y, n, true, Kneg);
    }
    if (t == 0) out[0] = total / (float)(4 * p);
}

extern "C" void kernel_launch(void* const* d_in, const int* in_sizes, int n_in,
                              void* d_out, int out_size, void* d_ws, size_t ws_size,
                              hipStream_t stream) {
    const float* x = (const float*)d_in[0];
    const float* y = (const float*)d_in[1];
    const int* pos_num = (const int*)d_in[2];
    float* out = (float*)d_out;
    const int n = in_sizes[0];

    unsigned* ws = (unsigned*)d_ws;
    const size_t wsw = ws_size / 4;
    unsigned cap_words = 0u;
    if (wsw > (size_t)OFF_CAND) cap_words = (unsigned)(wsw - OFF_CAND);
    if (cap_words > (unsigned)CANDW) cap_words = (unsigned)CANDW;
    unsigned side_cap = SIDE_CAP;
    if (wsw <= (size_t)OFF_CAND) side_cap = 0u;

    k_main<<<2048, 256, 0, stream>>>(x, y, ws, cap_words, n);
    k_hist<<<NP, 1024, 0, stream>>>(ws, pos_num);
    k_sel<<<NSEL, 1024, 0, stream>>>(ws, pos_num, side_cap);
    k_fin<<<1, 1024, 0, stream>>>(x, y, ws, pos_num, out, n, side_cap);
}